// Round 12
// baseline (183.859 us; speedup 1.0000x reference)
//
#include <hip/hip_runtime.h>
#include <hip/hip_bf16.h>

#define NROWS 131072
#define KIN   784
#define H1N   128
#define H2N   64
#define OUTN  10

// packed weights in d_ws (dwords): w1p 12800 | w2p 1024 | w3p 128 = 13952
#define W1P_DW 12800
#define W2P_DW 1024
#define W3P_DW 128
#define WTOT_DW (W1P_DW + W2P_DW + W3P_DW)

// LDS layout (bytes)
#define OFF_W1P   0          // 51200
#define OFF_W2P   51200      // 4096
#define OFF_W3P   55296      // 512
#define ROW_STR   1616       // half-row slot stride (16B aligned, bank-safe)
#define SLOT_SZ   (16 * ROW_STR)          // 25856
#define OFF_SLOT0 55808
#define OFF_SLOT1 (OFF_SLOT0 + SLOT_SZ)   // 81664
#define OFF_H1    107520     // [16][136] shorts = 4352
#define OFF_H2    111872     // [16][72]  shorts = 2304
#define OFF_OB    114176     // 160 f32 = 640
#define LDS_BYTES 114816

typedef short s16x8 __attribute__((ext_vector_type(8)));
typedef float f32x4 __attribute__((ext_vector_type(4)));
typedef __hip_bfloat16 bf16;

static __device__ __forceinline__ short b2s(float f) {
    bf16 h = __float2bfloat16(f);
    return *reinterpret_cast<short*>(&h);
}
static __device__ __forceinline__ s16x8 cvt8(f32x4 a, f32x4 b) {
    s16x8 r;
    r[0] = b2s(a[0]); r[1] = b2s(a[1]); r[2] = b2s(a[2]); r[3] = b2s(a[3]);
    r[4] = b2s(b[0]); r[5] = b2s(b[1]); r[6] = b2s(b[2]); r[7] = b2s(b[3]);
    return r;
}
// 8 int4 nibbles -> bf16x8 (values -8..7 exact)
static __device__ __forceinline__ s16x8 unpack8(unsigned d) {
    s16x8 r;
#pragma unroll
    for (int j = 0; j < 8; ++j) {
        int v = ((int)(d << (28 - 4 * j))) >> 28;
        r[j] = b2s((float)v);
    }
    return r;
}
static __device__ __forceinline__ void gl2lds16(const void* g, char* l) {
    __builtin_amdgcn_global_load_lds(
        (const __attribute__((address_space(1))) void*)g,
        (__attribute__((address_space(3))) void*)l, 16, 0, 0);
}

#define WAITV(N) do { asm volatile("s_waitcnt vmcnt(" #N ")" ::: "memory"); \
                      __builtin_amdgcn_sched_barrier(0); } while (0)
#define WAITL()  do { asm volatile("s_waitcnt lgkmcnt(0)" ::: "memory"); \
                      __builtin_amdgcn_sched_barrier(0); } while (0)
#define BAR()    __builtin_amdgcn_s_barrier()

// ---------------- prep: pack all weights to int4 nibble dwords ---------------
__global__ __launch_bounds__(256) void dequant_kernel(
    const int* __restrict__ w1q, const int* __restrict__ w2q,
    const int* __restrict__ w3q, unsigned* __restrict__ wpk)
{
    for (int i = blockIdx.x * blockDim.x + threadIdx.x; i < WTOT_DW;
         i += gridDim.x * blockDim.x) {
        unsigned d = 0;
        if (i < W1P_DW) {
            int kb = i >> 9, rem = i & 511;
            int kg = rem >> 7, col_s = rem & 127;
            int col = (col_s - 8 * kg) & 127;
#pragma unroll
            for (int j = 0; j < 8; ++j) {
                int k = kb * 32 + kg * 8 + j;
                unsigned q = 0;
                if (k < KIN) q = (unsigned)w1q[col * KIN + k] & 0xFu;
                d |= q << (4 * j);
            }
        } else if (i < W1P_DW + W2P_DW) {
            int t = i - W1P_DW;
            int kb = t >> 8, rem = t & 255;
            int kg = rem >> 6, col = rem & 63;
#pragma unroll
            for (int j = 0; j < 8; ++j) {
                int k = kb * 32 + kg * 8 + j;
                d |= ((unsigned)w2q[col * H1N + k] & 0xFu) << (4 * j);
            }
        } else {
            int t = i - W1P_DW - W2P_DW;
            int kb = t >> 6, rem = t & 63;
            int kg = rem >> 4, col = rem & 15;
            if (col < OUTN) {
#pragma unroll
                for (int j = 0; j < 8; ++j) {
                    int k = kb * 32 + kg * 8 + j;
                    d |= ((unsigned)w3q[col * H2N + k] & 0xFu) << (4 * j);
                }
            }
        }
        wpk[i] = d;
    }
}

// ---------------- fused MLP: sequential-stream design ------------------------
// 256 blocks (1/CU), 512 thr (8 waves). Block b owns rows [b*512, b*512+512),
// processed as 32 tiles of 16 rows; x fetched IN MEMORY ORDER as half-rows
// (1.5KB sequential runs) via gl_lds into a 2-slot ring (counted vmcnt, raw
// barriers). ALL weights live in LDS as int4 (loaded once) -> the loop's vmem
// stream is pure A. Wave w owns h1 cols 16w..16w+15 (acc=4 VGPR, no reduce).
__global__ __launch_bounds__(512, 2) void mlp_kernel(
    const float* __restrict__ x,
    const unsigned* __restrict__ wpk,
    const float* __restrict__ s1, const float* __restrict__ b1,
    const float* __restrict__ s2, const float* __restrict__ b2,
    const float* __restrict__ s3, const float* __restrict__ b3,
    float* __restrict__ out)
{
    extern __shared__ __align__(16) char lds[];
    const int tid  = threadIdx.x;
    const int lane = tid & 63;
    const int wv   = tid >> 6;      // 0..7
    const int r16  = lane & 15;
    const int kg   = lane >> 4;     // 0..3

    // ---- weights -> LDS (once) ----
    {
        unsigned* lw = (unsigned*)lds;
        for (int i = tid; i < WTOT_DW; i += 512) lw[i] = wpk[i];
    }
    const int col1 = wv * 16 + r16;                 // owned h1 col
    const float s1v = s1[col1], b1v = b1[col1];
    const int col2 = (wv < 4) ? wv * 16 + r16 : 0;  // owned h2 col
    const float s2v = s2[col2], b2v = b2[col2];
    const int col3 = (r16 < OUTN) ? r16 : 0;
    const float s3v = s3[col3], b3v = b3[col3];
    __syncthreads();

    const long long rowBlk = (long long)blockIdx.x * 512;
    const int mlim0 = 32, mlim1 = 36;   // masked-lane counts for 2nd instr

    // fetch half h (tile h>>1, part h&1) into slot (h&1): 4 gl_lds per wave
#define FETCH_HALF(H) do {                                                    \
        const int t_ = (H) >> 1, p_ = (H) & 1;                                \
        char* slot_ = lds + OFF_SLOT0 + ((H) & 1) * SLOT_SZ;                  \
        const float* gr_ = x + (rowBlk + t_ * 16 + 2 * wv) * (long long)KIN;  \
        const char* g_ = (const char*)gr_ + (p_ ? 1536 : 0);                  \
        char* d_ = slot_ + (2 * wv) * ROW_STR;                                \
        const int ml_ = p_ ? mlim1 : mlim0;                                   \
        gl2lds16(g_ + lane * 16, d_);                                         \
        if (lane < ml_) gl2lds16(g_ + 1024 + lane * 16, d_ + 1024);           \
        const char* g2_ = g_ + KIN * 4;                                       \
        char* d2_ = d_ + ROW_STR;                                             \
        gl2lds16(g2_ + lane * 16, d2_);                                       \
        if (lane < ml_) gl2lds16(g2_ + 1024 + lane * 16, d2_ + 1024);         \
    } while (0)

    // prologue: halves 0,1
    FETCH_HALF(0);
    FETCH_HALF(1);

    f32x4 acc1 = (f32x4){0.f, 0.f, 0.f, 0.f};

#pragma unroll 1
    for (int h = 0; h < 64; ++h) {
        const int p = h & 1;
        if (h == 63) { WAITV(0); } else { WAITV(4); }
        BAR();                     // all waves' half-h data landed

        const char* sl = lds + OFF_SLOT0 + (h & 1) * SLOT_SZ + r16 * ROW_STR;
        if (p == 0) {
            acc1 = (f32x4){0.f, 0.f, 0.f, 0.f};
#pragma unroll
            for (int w = 0; w < 12; ++w) {
                f32x4 q0 = *(const f32x4*)(sl + w * 128 + kg * 32);
                f32x4 q1 = *(const f32x4*)(sl + w * 128 + kg * 32 + 16);
                unsigned bd = *(const unsigned*)(lds + OFF_W1P +
                    ((w * 512) + kg * 128 + ((col1 + 8 * kg) & 127)) * 4);
                acc1 = __builtin_amdgcn_mfma_f32_16x16x32_bf16(
                    cvt8(q0, q1), unpack8(bd), acc1, 0, 0, 0);
            }
        } else {
#pragma unroll
            for (int w = 0; w < 12; ++w) {       // windows 12..23
                f32x4 q0 = *(const f32x4*)(sl + w * 128 + kg * 32);
                f32x4 q1 = *(const f32x4*)(sl + w * 128 + kg * 32 + 16);
                unsigned bd = *(const unsigned*)(lds + OFF_W1P +
                    (((w + 12) * 512) + kg * 128 + ((col1 + 8 * kg) & 127)) * 4);
                acc1 = __builtin_amdgcn_mfma_f32_16x16x32_bf16(
                    cvt8(q0, q1), unpack8(bd), acc1, 0, 0, 0);
            }
            {   // window 24: k 768..783 valid (kg 0,1), rest zero
                f32x4 q0 = (f32x4){0.f,0.f,0.f,0.f}, q1 = q0;
                if (kg < 2) {
                    q0 = *(const f32x4*)(sl + 1536 + kg * 32);
                    q1 = *(const f32x4*)(sl + 1536 + kg * 32 + 16);
                }
                unsigned bd = *(const unsigned*)(lds + OFF_W1P +
                    ((24 * 512) + kg * 128 + ((col1 + 8 * kg) & 127)) * 4);
                acc1 = __builtin_amdgcn_mfma_f32_16x16x32_bf16(
                    cvt8(q0, q1), unpack8(bd), acc1, 0, 0, 0);
            }
            // h1 epilogue: fold scale, bias, relu -> h1[16][136]
#pragma unroll
            for (int r = 0; r < 4; ++r) {
                const int row = kg * 4 + r;
                *(short*)(lds + OFF_H1 + row * 272 + col1 * 2) =
                    b2s(fmaxf(acc1[r] * s1v + b1v, 0.0f));
            }
        }

        WAITL();                   // my ds reads/writes complete
        BAR();                     // slot h free; h1 (if odd) visible

        if (h + 2 < 64) FETCH_HALF(h + 2);

        if (p) {
            // ---- layer 2: waves 0..3, 16 cols each ----
            if (wv < 4) {
                f32x4 acc2 = (f32x4){0.f, 0.f, 0.f, 0.f};
#pragma unroll
                for (int kb = 0; kb < 4; ++kb) {
                    s16x8 a = *(const s16x8*)(lds + OFF_H1 + r16 * 272 +
                                              (kb * 32 + kg * 8) * 2);
                    unsigned bd = *(const unsigned*)(lds + OFF_W2P +
                        (kb * 256 + kg * 64 + col2) * 4);
                    acc2 = __builtin_amdgcn_mfma_f32_16x16x32_bf16(
                        a, unpack8(bd), acc2, 0, 0, 0);
                }
#pragma unroll
                for (int r = 0; r < 4; ++r) {
                    const int row = kg * 4 + r;
                    *(short*)(lds + OFF_H2 + row * 144 + col2 * 2) =
                        b2s(fmaxf(acc2[r] * s2v + b2v, 0.0f));
                }
            }
            WAITL();
            BAR();                 // h2 visible
            // ---- layer 3 + output: wave 0 only ----
            if (wv == 0) {
                f32x4 acc3 = (f32x4){0.f, 0.f, 0.f, 0.f};
#pragma unroll
                for (int kb = 0; kb < 2; ++kb) {
                    s16x8 a = *(const s16x8*)(lds + OFF_H2 + r16 * 144 +
                                              (kb * 32 + kg * 8) * 2);
                    unsigned bd = *(const unsigned*)(lds + OFF_W3P +
                        (kb * 64 + kg * 16 + r16) * 4);
                    acc3 = __builtin_amdgcn_mfma_f32_16x16x32_bf16(
                        a, unpack8(bd), acc3, 0, 0, 0);
                }
                float* ob = (float*)(lds + OFF_OB);
#pragma unroll
                for (int r = 0; r < 4; ++r) {
                    const int row = kg * 4 + r;
                    if (r16 < OUTN) ob[row * OUTN + r16] = acc3[r] * s3v + b3v;
                }
                const long long obase = (rowBlk + (long long)(h >> 1) * 16) * OUTN;
                for (int i = lane; i < 16 * OUTN; i += 64) out[obase + i] = ob[i];
            }
        }
    }
#undef FETCH_HALF
}

extern "C" void kernel_launch(void* const* d_in, const int* in_sizes, int n_in,
                              void* d_out, int out_size, void* d_ws, size_t ws_size,
                              hipStream_t stream) {
    const float* x   = (const float*)d_in[0];
    const int*   w1q = (const int*)d_in[1];
    const float* s1  = (const float*)d_in[2];
    const float* b1  = (const float*)d_in[3];
    const int*   w2q = (const int*)d_in[4];
    const float* s2  = (const float*)d_in[5];
    const float* b2  = (const float*)d_in[6];
    const int*   w3q = (const int*)d_in[7];
    const float* s3  = (const float*)d_in[8];
    const float* b3  = (const float*)d_in[9];
    float* out = (float*)d_out;

    unsigned* wpk = (unsigned*)d_ws;   // 13952 dwords

    static int attr_set = 0;
    if (!attr_set) {
        hipFuncSetAttribute((const void*)mlp_kernel,
                            hipFuncAttributeMaxDynamicSharedMemorySize, LDS_BYTES);
        attr_set = 1;
    }

    dequant_kernel<<<64, 256, 0, stream>>>(w1q, w2q, w3q, wpk);
    mlp_kernel<<<256, 512, LDS_BYTES, stream>>>(x, wpk, s1, b1, s2, b2, s3, b3, out);
}

// Round 13
// 152.346 us; speedup vs baseline: 1.2068x; 1.2068x over previous
//
#include <hip/hip_runtime.h>
#include <hip/hip_bf16.h>

#define NROWS 131072
#define KIN   784
#define H1N   128
#define H2N   64
#define OUTN  10
#define NTILES 2048   // 64-row tiles

// chunked weight layouts: w1c[kb][col][8] with kb = k/8  (k in [0,800))
#define W1C_ELEMS (100 * 128 * 8)   // 102400
#define W2C_ELEMS (16 * 64 * 8)     // 8192
#define W3_ELEMS  (16 * 64)         // 1024

typedef short s16x8 __attribute__((ext_vector_type(8)));
typedef float f32x4 __attribute__((ext_vector_type(4)));

typedef __hip_bfloat16 bf16;

static __device__ __forceinline__ short b2s(float f) {
    bf16 h = __float2bfloat16(f);
    return *reinterpret_cast<short*>(&h);
}

static __device__ __forceinline__ s16x8 cvt8(f32x4 a, f32x4 b) {
    s16x8 r;
    r[0] = b2s(a[0]); r[1] = b2s(a[1]); r[2] = b2s(a[2]); r[3] = b2s(a[3]);
    r[4] = b2s(b[0]); r[5] = b2s(b[1]); r[6] = b2s(b[2]); r[7] = b2s(b[3]);
    return r;
}

// async global -> LDS: 16B/lane, per-lane global addr, wave-uniform LDS base
static __device__ __forceinline__ void gl2lds16(const void* g, char* l) {
    __builtin_amdgcn_global_load_lds(
        (const __attribute__((address_space(1))) void*)g,
        (__attribute__((address_space(3))) void*)l, 16, 0, 0);
}

#define WAITV(N) do { asm volatile("s_waitcnt vmcnt(" #N ")" ::: "memory"); \
                      __builtin_amdgcn_sched_barrier(0); } while (0)
#define WAITL()  do { asm volatile("s_waitcnt lgkmcnt(0)" ::: "memory"); \
                      __builtin_amdgcn_sched_barrier(0); } while (0)
#define BAR()    __builtin_amdgcn_s_barrier()

// ---------------- dequant: int4(int32) * f32 scale -> bf16 (chunked layouts) --
__global__ __launch_bounds__(256) void dequant_kernel(
    const int* __restrict__ w1q, const float* __restrict__ s1,
    const int* __restrict__ w2q, const float* __restrict__ s2,
    const int* __restrict__ w3q, const float* __restrict__ s3,
    bf16* __restrict__ w1c, bf16* __restrict__ w2c, bf16* __restrict__ w3d,
    int* __restrict__ cnt)
{
    if (blockIdx.x == 0 && threadIdx.x == 0) *cnt = 0;   // reset every launch
    const int total = W1C_ELEMS + W2C_ELEMS + W3_ELEMS;
    for (int i = blockIdx.x * blockDim.x + threadIdx.x; i < total;
         i += gridDim.x * blockDim.x) {
        if (i < W1C_ELEMS) {
            int kb = i >> 10, rem = i & 1023;
            int col = rem >> 3, j = rem & 7;
            int k = kb * 8 + j;
            float v = 0.0f;
            if (k < KIN) v = (float)w1q[col * KIN + k] * s1[col];
            w1c[i] = __float2bfloat16(v);
        } else if (i < W1C_ELEMS + W2C_ELEMS) {
            int t = i - W1C_ELEMS;
            int kb = t >> 9, rem = t & 511;
            int col = rem >> 3, j = rem & 7;
            int k = kb * 8 + j;
            w2c[t] = __float2bfloat16((float)w2q[col * H1N + k] * s2[col]);
        } else {
            int t = i - W1C_ELEMS - W2C_ELEMS;
            int r = t >> 6, c = t & 63;
            float v = 0.0f;
            if (r < OUTN) v = (float)w3q[r * H2N + c] * s3[r];
            w3d[t] = __float2bfloat16(v);
        }
    }
}

// ---------------- fused MLP (persistent, atomic tile queue) -----------------
// The 112us champion structure, unchanged: 256 thr (4 waves), 64-row tile,
// wave owns 16 rows; A+B staged via global_load_lds into a 2-slot block ring
// (A 8KB + B 8KB per slot), uniform 4-op/window vmem stream, WAITV(4) keeps
// ~2 windows airborne, 2 raw s_barriers/window. LDS 32KB -> 5 blocks/CU =
// 20 waves. NEW: grid 1280 (exactly 5/CU) with tiles pulled from a global
// atomic counter -> 20 waves/CU sustained, no 1.6-round dispatch tail.
__global__ __launch_bounds__(256, 5) void mlp_kernel(
    const float* __restrict__ x,
    const bf16*  __restrict__ w1c,
    const bf16*  __restrict__ w2c,
    const bf16*  __restrict__ w3d,
    const float* __restrict__ b1,
    const float* __restrict__ b2,
    const float* __restrict__ b3,
    float* __restrict__ out,
    int* __restrict__ cnt)
{
    __shared__ __align__(16) char lds[32768];
    // slot s at lds+s*16384: A [0,8192) (wave wv at +wv*2048, 16 rows x 128B,
    // seg-swizzled), B [8192,16384) = verbatim w1c k-window (4 kb-chunks).
    // post-loop arenas: lds + wv*4224; lds[0..3] doubles as the tile mailbox.

    const int tid  = threadIdx.x;
    const int lane = tid & 63;
    const int wv   = tid >> 6;
    const int r16  = lane & 15;
    const int kg   = lane >> 4;     // 0..3
    const int kgo  = kg * 8;

    const int i3 = lane >> 3;       // staging row-in-group 0..7
    const int i7 = lane & 7;        // staging LDS 16B-slot 0..7
    const int sw = i7 ^ i3;         // swizzled global seg index
    const int adj = (sw >= 4) ? 16 : 0;   // tail-window in-row redirect

    // consume offsets (slot-relative)
    const int aoff0 = wv * 2048 + r16 * 128 + (((2 * kg) ^ (r16 & 7)) * 16);
    const int aoff1 = wv * 2048 + r16 * 128 + (((2 * kg + 1) ^ (r16 & 7)) * 16);
    const int boff  = 8192 + kg * 2048 + r16 * 16;
    const bf16* gB  = w1c + (size_t)wv * 1024 + (size_t)lane * 8;

    for (;;) {
        // ---- pull next tile (boundary: pipeline already drained) ----
        if (tid == 0) *(volatile int*)lds = atomicAdd(cnt, 1);
        __syncthreads();
        const int tile = *(volatile int*)lds;
        __syncthreads();            // everyone has `tile` before staging clobbers
        if (tile >= NTILES) return;

        const long long rowW = (long long)tile * 64 + wv * 16;
        const float* gA0 = x + (rowW + i3) * (long long)KIN + sw * 4;      // rows 0-7
        const float* gA1 = x + (rowW + 8 + i3) * (long long)KIN + sw * 4;  // rows 8-15

        // prologue: stage windows 0,1 into slots 0,1 (4 gl_lds each per wave)
#pragma unroll
        for (int w = 0; w < 2; ++w) {
            char* sd = lds + w * 16384;
            gl2lds16(gA0 + w * 32, sd + wv * 2048);
            gl2lds16(gA1 + w * 32, sd + wv * 2048 + 1024);
            const bf16* gw = gB + (size_t)w * 4096;
            gl2lds16(gw,       sd + 8192 + wv * 2048);
            gl2lds16(gw + 512, sd + 8192 + wv * 2048 + 1024);
        }

        f32x4 acc1[8];
#pragma unroll
        for (int j = 0; j < 8; ++j) acc1[j] = (f32x4){0.f, 0.f, 0.f, 0.f};

#pragma unroll 1
        for (int t = 0; t < 24; ++t) {
            WAITV(4);                 // this wave's window-t gl_lds retired
            BAR();                    // all waves' shares landed
            const char* sb = lds + (t & 1) * 16384;
            f32x4 q0 = *(const f32x4*)(sb + aoff0);
            f32x4 q1 = *(const f32x4*)(sb + aoff1);
            s16x8 bw[8];
#pragma unroll
            for (int nj = 0; nj < 8; ++nj)
                bw[nj] = *(const s16x8*)(sb + boff + nj * 256);
            WAITL();                  // reads are in registers
            BAR();                    // all waves done reading slot t&1
            char* sd = lds + (t & 1) * 16384;
            const int w = t + 2;
            if (w < 24) {
                gl2lds16(gA0 + w * 32, sd + wv * 2048);
                gl2lds16(gA1 + w * 32, sd + wv * 2048 + 1024);
                const bf16* gw = gB + (size_t)w * 4096;
                gl2lds16(gw,       sd + 8192 + wv * 2048);
                gl2lds16(gw + 512, sd + 8192 + wv * 2048 + 1024);
            } else if (w == 24) {     // tail window: segs 4-7 redirect in-bounds
                gl2lds16(gA0 + 768 - adj, sd + wv * 2048);
                gl2lds16(gA1 + 768 - adj, sd + wv * 2048 + 1024);
                const bf16* gw = gB + (size_t)24 * 4096;
                gl2lds16(gw,       sd + 8192 + wv * 2048);
                gl2lds16(gw + 512, sd + 8192 + wv * 2048 + 1024);
            }
            s16x8 a = cvt8(q0, q1);
#pragma unroll
            for (int nj = 0; nj < 8; ++nj)
                acc1[nj] = __builtin_amdgcn_mfma_f32_16x16x32_bf16(a, bw[nj], acc1[nj], 0, 0, 0);
        }
        {   // peeled window 24 (k 768-799; weights zero for k>=784)
            WAITV(0);
            BAR();
            const char* sb = lds;     // slot 0
            f32x4 q0 = *(const f32x4*)(sb + aoff0);
            f32x4 q1 = *(const f32x4*)(sb + aoff1);
            s16x8 bw[8];
#pragma unroll
            for (int nj = 0; nj < 8; ++nj)
                bw[nj] = *(const s16x8*)(sb + boff + nj * 256);
            WAITL();
            BAR();                    // ring fully dead -> arenas may overlay
            s16x8 a = cvt8(q0, q1);
#pragma unroll
            for (int nj = 0; nj < 8; ++nj)
                acc1[nj] = __builtin_amdgcn_mfma_f32_16x16x32_bf16(a, bw[nj], acc1[nj], 0, 0, 0);
        }

        // ---- per-wave arena: h1[16][132] -> h2[16][68] -> out stage ---------
        char* ar = lds + wv * 4224;
        short (*h1w)[132] = (short(*)[132])ar;
#pragma unroll
        for (int nj = 0; nj < 8; ++nj) {
            const int col = nj * 16 + r16;
            const float bb = b1[col];
#pragma unroll
            for (int r = 0; r < 4; ++r)
                h1w[kg * 4 + r][col] = b2s(fmaxf(acc1[nj][r] + bb, 0.0f));
        }

        // ---- layer 2: [16 x 128] @ [128 x 64] per wave ----
        f32x4 acc2[4];
#pragma unroll
        for (int j = 0; j < 4; ++j) acc2[j] = (f32x4){0.f, 0.f, 0.f, 0.f};

#pragma unroll
        for (int it = 0; it < 4; ++it) {
            const int kk = it * 32 + kgo;
            s16x8 a = *(const s16x8*)&h1w[r16][kk];
            const bf16* bp2 = w2c + (size_t)(it * 4 + kg) * 512 + (size_t)r16 * 8;
#pragma unroll
            for (int nj = 0; nj < 4; ++nj) {
                s16x8 b = *(const s16x8*)(bp2 + nj * 128);
                acc2[nj] = __builtin_amdgcn_mfma_f32_16x16x32_bf16(a, b, acc2[nj], 0, 0, 0);
            }
        }

        short (*h2w)[68] = (short(*)[68])ar;   // same-wave overlay
#pragma unroll
        for (int nj = 0; nj < 4; ++nj) {
            const int col = nj * 16 + r16;
            const float bb = b2[col];
#pragma unroll
            for (int r = 0; r < 4; ++r)
                h2w[kg * 4 + r][col] = b2s(fmaxf(acc2[nj][r] + bb, 0.0f));
        }

        // ---- layer 3: [16 x 64] @ [64 x 16] (rows 10..15 of W3 are zero) ----
        f32x4 acc3 = (f32x4){0.f, 0.f, 0.f, 0.f};
#pragma unroll
        for (int it = 0; it < 2; ++it) {
            const int kk = it * 32 + kgo;
            s16x8 a = *(const s16x8*)&h2w[r16][kk];
            s16x8 b = *(const s16x8*)(w3d + r16 * H2N + kk);
            acc3 = __builtin_amdgcn_mfma_f32_16x16x32_bf16(a, b, acc3, 0, 0, 0);
        }

        float* ob = (float*)ar;   // 640B out stage, overlay after h2 reads
        const float bb3 = (r16 < OUTN) ? b3[r16] : 0.0f;
#pragma unroll
        for (int r = 0; r < 4; ++r) {
            const int row = kg * 4 + r;
            if (r16 < OUTN) ob[row * OUTN + r16] = acc3[r] + bb3;
        }
        const long long obase = rowW * OUTN;
        for (int i = lane; i < 16 * OUTN; i += 64) out[obase + i] = ob[i];

        __syncthreads();   // arenas done block-wide before next tile's mailbox
    }
}

extern "C" void kernel_launch(void* const* d_in, const int* in_sizes, int n_in,
                              void* d_out, int out_size, void* d_ws, size_t ws_size,
                              hipStream_t stream) {
    const float* x   = (const float*)d_in[0];
    const int*   w1q = (const int*)d_in[1];
    const float* s1  = (const float*)d_in[2];
    const float* b1  = (const float*)d_in[3];
    const int*   w2q = (const int*)d_in[4];
    const float* s2  = (const float*)d_in[5];
    const float* b2  = (const float*)d_in[6];
    const int*   w3q = (const int*)d_in[7];
    const float* s3  = (const float*)d_in[8];
    const float* b3  = (const float*)d_in[9];
    float* out = (float*)d_out;

    bf16* w1c = (bf16*)d_ws;              // [100][128][8]
    bf16* w2c = w1c + W1C_ELEMS;          // [16][64][8]
    bf16* w3d = w2c + W2C_ELEMS;          // [16][64]
    int*  cnt = (int*)(w3d + W3_ELEMS);   // tile queue counter

    dequant_kernel<<<128, 256, 0, stream>>>(w1q, s1, w2q, s2, w3q, s3,
                                            w1c, w2c, w3d, cnt);
    mlp_kernel<<<1280, 256, 0, stream>>>(x, w1c, w2c, w3d, b1, b2, b3, out, cnt);
}

// Round 14
// 95.545 us; speedup vs baseline: 1.9243x; 1.5945x over previous
//
#include <hip/hip_runtime.h>
#include <hip/hip_bf16.h>

#define NROWS 131072
#define KIN   784
#define H1N   128
#define H2N   64
#define OUTN  10

// packed W1: w1p[kb][kg][col_s] dword; kb=0..24, kg=0..3, col_s=(col+8*kg)&127,
// nibble j = int4 of w1q[col][kb*32+kg*8+j] (zero for k>=784).
#define W1P_DW    12800
#define W2C_ELEMS (16 * 64 * 8)    // bf16, k-chunked
#define W3_ELEMS  (16 * 64)        // bf16

typedef short s16x8 __attribute__((ext_vector_type(8)));
typedef float f32x4 __attribute__((ext_vector_type(4)));
typedef __hip_bfloat16 bf16;

static __device__ __forceinline__ short b2s(float f) {
    bf16 h = __float2bfloat16(f);
    return *reinterpret_cast<short*>(&h);
}
static __device__ __forceinline__ s16x8 cvt8(f32x4 a, f32x4 b) {
    s16x8 r;
    r[0] = b2s(a[0]); r[1] = b2s(a[1]); r[2] = b2s(a[2]); r[3] = b2s(a[3]);
    r[4] = b2s(b[0]); r[5] = b2s(b[1]); r[6] = b2s(b[2]); r[7] = b2s(b[3]);
    return r;
}
// 8 int4 nibbles -> bf16x8 (values -8..7 exact in bf16)
static __device__ __forceinline__ s16x8 unpack8(unsigned d) {
    s16x8 r;
#pragma unroll
    for (int j = 0; j < 8; ++j) {
        int v = ((int)(d << (28 - 4 * j))) >> 28;
        r[j] = b2s((float)v);
    }
    return r;
}
static __device__ __forceinline__ void gl2lds16(const void* g, char* l) {
    __builtin_amdgcn_global_load_lds(
        (const __attribute__((address_space(1))) void*)g,
        (__attribute__((address_space(3))) void*)l, 16, 0, 0);
}
static __device__ __forceinline__ void gl2lds4(const void* g, char* l) {
    __builtin_amdgcn_global_load_lds(
        (const __attribute__((address_space(1))) void*)g,
        (__attribute__((address_space(3))) void*)l, 4, 0, 0);
}

#define WAITV(N) do { asm volatile("s_waitcnt vmcnt(" #N ")" ::: "memory"); \
                      __builtin_amdgcn_sched_barrier(0); } while (0)
#define WAITL()  do { asm volatile("s_waitcnt lgkmcnt(0)" ::: "memory"); \
                      __builtin_amdgcn_sched_barrier(0); } while (0)
#define BAR()    __builtin_amdgcn_s_barrier()

// ---------------- prep: pack W1 int4; dequant W2/W3 to bf16 ------------------
__global__ __launch_bounds__(256) void dequant_kernel(
    const int* __restrict__ w1q, const float* __restrict__ s1,
    const int* __restrict__ w2q, const float* __restrict__ s2,
    const int* __restrict__ w3q, const float* __restrict__ s3,
    unsigned* __restrict__ w1p, bf16* __restrict__ w2c, bf16* __restrict__ w3d)
{
    const int total = W1P_DW + W2C_ELEMS + W3_ELEMS;
    for (int i = blockIdx.x * blockDim.x + threadIdx.x; i < total;
         i += gridDim.x * blockDim.x) {
        if (i < W1P_DW) {
            int kb = i >> 9, rem = i & 511;
            int kg = rem >> 7, col_s = rem & 127;
            int col = (col_s - 8 * kg) & 127;
            unsigned d = 0;
#pragma unroll
            for (int j = 0; j < 8; ++j) {
                int k = kb * 32 + kg * 8 + j;
                unsigned q = 0;
                if (k < KIN) q = (unsigned)w1q[col * KIN + k] & 0xFu;
                d |= q << (4 * j);
            }
            w1p[i] = d;
        } else if (i < W1P_DW + W2C_ELEMS) {
            int t = i - W1P_DW;
            int kb = t >> 9, rem = t & 511;
            int col = rem >> 3, j = rem & 7;
            int k = kb * 8 + j;
            w2c[t] = __float2bfloat16((float)w2q[col * H1N + k] * s2[col]);
        } else {
            int t = i - W1P_DW - W2C_ELEMS;
            int r = t >> 6, c = t & 63;
            float v = 0.0f;
            if (r < OUTN) v = (float)w3q[r * H2N + c] * s3[r];
            w3d[t] = __float2bfloat16(v);
        }
    }
}

// ---------------- fused MLP ------------------------------------------------
// r8 skeleton (256 thr / 64-row tile / 2-slot gl_lds ring / WAITV(4) depth-2 /
// 2 raw barriers / dispatch grid 2048), with:
//  - 2x2 wave decomposition: wave(rg=wv>>1, cg=wv&1) computes 32 rows x 64
//    cols -> B-frag reads per wave halved, LDS read traffic 40->27KB/window.
//  - W1 staged as PACKED INT4 (2KB/window vs 8KB bf16), unpacked in-reg;
//    scale folded out of the K-loop (exact int accumulate, x*s in epilogue).
__global__ __launch_bounds__(256, 5) void mlp_kernel(
    const float* __restrict__ x,
    const unsigned* __restrict__ w1p,
    const bf16*  __restrict__ w2c,
    const bf16*  __restrict__ w3d,
    const float* __restrict__ s1,
    const float* __restrict__ b1,
    const float* __restrict__ b2,
    const float* __restrict__ b3,
    float* __restrict__ out)
{
    __shared__ __align__(16) char lds[25600];
    // A slots: [0,8K),[8K,16K): 64 rows x 128B (row r at r*128, seg-swizzled)
    // B slots: [16K,18K),[18K,20K): packed window, 512 dwords [kg][col_s]
    // post-loop: h1 [64][132] shorts at 0 (16896B); h2 [64][68] at 16896.

    const int tid  = threadIdx.x;
    const int lane = tid & 63;
    const int wv   = tid >> 6;
    const int r16  = lane & 15;
    const int kg   = lane >> 4;     // 0..3
    const int kgo  = kg * 8;
    const int rg   = wv >> 1;       // row group 0..1 (32 rows)
    const int cg   = wv & 1;        // col group 0..1 (64 cols)

    const int i3 = lane >> 3;       // staging row-in-group 0..7
    const int i7 = lane & 7;        // staging 16B-slot 0..7
    const int sw = i7 ^ i3;         // swizzled global seg
    const int adj = (sw >= 4) ? 16 : 0;

    const long long rowBlk = (long long)blockIdx.x * 64;
    const float* gA0 = x + (rowBlk + wv * 16 + i3) * (long long)KIN + sw * 4;
    const float* gA1 = gA0 + 8LL * KIN;
    const unsigned* gBp = w1p + wv * 128 + lane;

    // consume offsets: rows rg*32 + mi*16 + r16 (mi=0 base; mi=1 at +2048)
    const int aoff = (rg * 32 + r16) * 128 + (((2 * kg) ^ (r16 & 7)) * 16);
    // B frag nj: kg*512 + ((cg*64 + nj*16 + r16 + 8*kg)&127)*4 within B slot
    const int bcol = cg * 64 + r16 + 8 * kg;

    // prologue: stage windows 0,1
#pragma unroll
    for (int w = 0; w < 2; ++w) {
        char* ad = lds + w * 8192 + wv * 2048;
        gl2lds16(gA0 + w * 32, ad);
        gl2lds16(gA1 + w * 32, ad + 1024);
        char* bd = lds + 16384 + w * 2048 + wv * 512;
        gl2lds4(gBp + w * 512, bd);
        gl2lds4(gBp + w * 512 + 64, bd + 256);
    }

    f32x4 acc1[2][4];
#pragma unroll
    for (int i = 0; i < 2; ++i)
#pragma unroll
        for (int j = 0; j < 4; ++j) acc1[i][j] = (f32x4){0.f, 0.f, 0.f, 0.f};

#pragma unroll 1
    for (int t = 0; t < 24; ++t) {
        WAITV(4);                 // window t's 4 ops retired (t+1 airborne)
        BAR();                    // all waves' shares landed
        const char* sa = lds + (t & 1) * 8192;
        f32x4 q00 = *(const f32x4*)(sa + aoff);
        f32x4 q01 = *(const f32x4*)(sa + (aoff ^ 16));
        f32x4 q10 = *(const f32x4*)(sa + aoff + 2048);
        f32x4 q11 = *(const f32x4*)(sa + (aoff ^ 16) + 2048);
        const char* sb = lds + 16384 + (t & 1) * 2048 + kg * 512;
        unsigned bw4[4];
#pragma unroll
        for (int nj = 0; nj < 4; ++nj)
            bw4[nj] = *(const unsigned*)(sb + (((bcol + nj * 16) & 127) << 2));
        WAITL();                  // reads in registers
        BAR();                    // all waves done with slot t&1
        {   // stage window t+2 into the freed slot
            const int w = t + 2;
            char* ad = lds + (t & 1) * 8192 + wv * 2048;
            char* bd = lds + 16384 + (t & 1) * 2048 + wv * 512;
            if (w < 24) {
                gl2lds16(gA0 + w * 32, ad);
                gl2lds16(gA1 + w * 32, ad + 1024);
                gl2lds4(gBp + w * 512, bd);
                gl2lds4(gBp + w * 512 + 64, bd + 256);
            } else if (w == 24) { // tail: segs>=4 redirected in-row
                gl2lds16(gA0 + 768 - adj, ad);
                gl2lds16(gA1 + 768 - adj, ad + 1024);
                gl2lds4(gBp + 24 * 512, bd);
                gl2lds4(gBp + 24 * 512 + 64, bd + 256);
            }
        }
        s16x8 a0 = cvt8(q00, q01);
        s16x8 a1 = cvt8(q10, q11);
#pragma unroll
        for (int nj = 0; nj < 4; ++nj) {
            s16x8 bf = unpack8(bw4[nj]);
            acc1[0][nj] = __builtin_amdgcn_mfma_f32_16x16x32_bf16(a0, bf, acc1[0][nj], 0, 0, 0);
            acc1[1][nj] = __builtin_amdgcn_mfma_f32_16x16x32_bf16(a1, bf, acc1[1][nj], 0, 0, 0);
        }
    }
    {   // peeled window 24 (k 768..799; packed weights zero for k>=784)
        WAITV(0);
        BAR();
        const char* sa = lds;     // slot 0
        f32x4 q00 = *(const f32x4*)(sa + aoff);
        f32x4 q01 = *(const f32x4*)(sa + (aoff ^ 16));
        f32x4 q10 = *(const f32x4*)(sa + aoff + 2048);
        f32x4 q11 = *(const f32x4*)(sa + (aoff ^ 16) + 2048);
        const char* sb = lds + 16384 + kg * 512;
        unsigned bw4[4];
#pragma unroll
        for (int nj = 0; nj < 4; ++nj)
            bw4[nj] = *(const unsigned*)(sb + (((bcol + nj * 16) & 127) << 2));
        WAITL();
        BAR();                    // ring fully dead -> arenas may overlay
        s16x8 a0 = cvt8(q00, q01);
        s16x8 a1 = cvt8(q10, q11);
#pragma unroll
        for (int nj = 0; nj < 4; ++nj) {
            s16x8 bf = unpack8(bw4[nj]);
            acc1[0][nj] = __builtin_amdgcn_mfma_f32_16x16x32_bf16(a0, bf, acc1[0][nj], 0, 0, 0);
            acc1[1][nj] = __builtin_amdgcn_mfma_f32_16x16x32_bf16(a1, bf, acc1[1][nj], 0, 0, 0);
        }
    }

    // ---- h1 (block-level [64][132] shorts at lds+0): scale+bias+relu -------
    short* h1s = (short*)lds;
#pragma unroll
    for (int nj = 0; nj < 4; ++nj) {
        const int col = cg * 64 + nj * 16 + r16;
        const float sc = s1[col];
        const float bb = b1[col];
#pragma unroll
        for (int mi = 0; mi < 2; ++mi)
#pragma unroll
            for (int r = 0; r < 4; ++r) {
                const int row = rg * 32 + mi * 16 + kg * 4 + r;
                h1s[row * 132 + col] = b2s(fmaxf(acc1[mi][nj][r] * sc + bb, 0.0f));
            }
    }
    __syncthreads();   // h1 rows cross wave boundaries

    // ---- layer 2: [16 x 128] @ [128 x 64] per wave (rows wv*16..) ----------
    f32x4 acc2[4];
#pragma unroll
    for (int j = 0; j < 4; ++j) acc2[j] = (f32x4){0.f, 0.f, 0.f, 0.f};

#pragma unroll
    for (int it = 0; it < 4; ++it) {
        const int kk = it * 32 + kgo;
        s16x8 a = *(const s16x8*)(h1s + (wv * 16 + r16) * 132 + kk);
        const bf16* bp2 = w2c + (size_t)(it * 4 + kg) * 512 + (size_t)r16 * 8;
#pragma unroll
        for (int nj = 0; nj < 4; ++nj) {
            s16x8 b = *(const s16x8*)(bp2 + nj * 128);
            acc2[nj] = __builtin_amdgcn_mfma_f32_16x16x32_bf16(a, b, acc2[nj], 0, 0, 0);
        }
    }

    // h2 at lds+16896: [64][68] shorts; wave writes/reads its own 16 rows
    short* h2s = (short*)(lds + 16896);
#pragma unroll
    for (int nj = 0; nj < 4; ++nj) {
        const int col = nj * 16 + r16;
        const float bb = b2[col];
#pragma unroll
        for (int r = 0; r < 4; ++r)
            h2s[(wv * 16 + kg * 4 + r) * 68 + col] = b2s(fmaxf(acc2[nj][r] + bb, 0.0f));
    }

    // ---- layer 3: [16 x 64] @ [64 x 16] (rows 10..15 of W3 zero) -----------
    f32x4 acc3 = (f32x4){0.f, 0.f, 0.f, 0.f};
#pragma unroll
    for (int it = 0; it < 2; ++it) {
        const int kk = it * 32 + kgo;
        s16x8 a = *(const s16x8*)(h2s + (wv * 16 + r16) * 68 + kk);
        s16x8 b = *(const s16x8*)(w3d + r16 * H2N + kk);
        acc3 = __builtin_amdgcn_mfma_f32_16x16x32_bf16(a, b, acc3, 0, 0, 0);
    }

    // out stage in wave's own (dead) h1 rows
    float* ob = (float*)(lds + (wv * 16) * 264);
    const float bb3 = (r16 < OUTN) ? b3[r16] : 0.0f;
#pragma unroll
    for (int r = 0; r < 4; ++r) {
        const int row = kg * 4 + r;
        if (r16 < OUTN) ob[row * OUTN + r16] = acc3[r] + bb3;
    }
    const long long obase = (rowBlk + wv * 16) * OUTN;
    for (int i = lane; i < 16 * OUTN; i += 64) out[obase + i] = ob[i];
}

extern "C" void kernel_launch(void* const* d_in, const int* in_sizes, int n_in,
                              void* d_out, int out_size, void* d_ws, size_t ws_size,
                              hipStream_t stream) {
    const float* x   = (const float*)d_in[0];
    const int*   w1q = (const int*)d_in[1];
    const float* s1  = (const float*)d_in[2];
    const float* b1  = (const float*)d_in[3];
    const int*   w2q = (const int*)d_in[4];
    const float* s2  = (const float*)d_in[5];
    const float* b2  = (const float*)d_in[6];
    const int*   w3q = (const int*)d_in[7];
    const float* s3  = (const float*)d_in[8];
    const float* b3  = (const float*)d_in[9];
    float* out = (float*)d_out;

    unsigned* w1p = (unsigned*)d_ws;           // 12800 dwords
    bf16* w2c = (bf16*)(w1p + W1P_DW);         // [16][64][8]
    bf16* w3d = w2c + W2C_ELEMS;               // [16][64]

    dequant_kernel<<<128, 256, 0, stream>>>(w1q, s1, w2q, s2, w3q, s3, w1p, w2c, w3d);
    mlp_kernel<<<NROWS / 64, 256, 0, stream>>>(x, w1p, w2c, w3d, s1, b1, b2, b3, out);
}

// Round 15
// 95.408 us; speedup vs baseline: 1.9271x; 1.0014x over previous
//
#include <hip/hip_runtime.h>
#include <hip/hip_bf16.h>

#define NROWS 131072
#define KIN   784
#define H1N   128
#define H2N   64
#define OUTN  10

// packed W1: w1p[kb][kg][col_s] dword; kb=0..24, kg=0..3, col_s=(col+8*kg)&127,
// nibble j = int4 of w1q[col][kb*32+kg*8+j] (zero for k>=784).
#define W1P_DW    12800
#define W2C_ELEMS (16 * 64 * 8)    // bf16, k-chunked
#define W3_ELEMS  (16 * 64)       // bf16

typedef short s16x8 __attribute__((ext_vector_type(8)));
typedef float f32x4 __attribute__((ext_vector_type(4)));
typedef __hip_bfloat16 bf16;

static __device__ __forceinline__ short b2s(float f) {
    bf16 h = __float2bfloat16(f);
    return *reinterpret_cast<short*>(&h);
}
static __device__ __forceinline__ s16x8 cvt8(f32x4 a, f32x4 b) {
    s16x8 r;
    r[0] = b2s(a[0]); r[1] = b2s(a[1]); r[2] = b2s(a[2]); r[3] = b2s(a[3]);
    r[4] = b2s(b[0]); r[5] = b2s(b[1]); r[6] = b2s(b[2]); r[7] = b2s(b[3]);
    return r;
}
// 8 int4 nibbles -> bf16x8 (values -8..7 exact in bf16)
static __device__ __forceinline__ s16x8 unpack8(unsigned d) {
    s16x8 r;
#pragma unroll
    for (int j = 0; j < 8; ++j) {
        int v = ((int)(d << (28 - 4 * j))) >> 28;
        r[j] = b2s((float)v);
    }
    return r;
}
static __device__ __forceinline__ void gl2lds16(const void* g, char* l) {
    __builtin_amdgcn_global_load_lds(
        (const __attribute__((address_space(1))) void*)g,
        (__attribute__((address_space(3))) void*)l, 16, 0, 0);
}
static __device__ __forceinline__ void gl2lds4(const void* g, char* l) {
    __builtin_amdgcn_global_load_lds(
        (const __attribute__((address_space(1))) void*)g,
        (__attribute__((address_space(3))) void*)l, 4, 0, 0);
}

#define WAITV(N) do { asm volatile("s_waitcnt vmcnt(" #N ")" ::: "memory"); \
                      __builtin_amdgcn_sched_barrier(0); } while (0)
#define WAITL()  do { asm volatile("s_waitcnt lgkmcnt(0)" ::: "memory"); \
                      __builtin_amdgcn_sched_barrier(0); } while (0)
#define BAR()    __builtin_amdgcn_s_barrier()

// ---------------- prep: pack W1 int4; dequant W2/W3 to bf16 ------------------
__global__ __launch_bounds__(256) void dequant_kernel(
    const int* __restrict__ w1q, const float* __restrict__ s1,
    const int* __restrict__ w2q, const float* __restrict__ s2,
    const int* __restrict__ w3q, const float* __restrict__ s3,
    unsigned* __restrict__ w1p, bf16* __restrict__ w2c, bf16* __restrict__ w3d)
{
    const int total = W1P_DW + W2C_ELEMS + W3_ELEMS;
    for (int i = blockIdx.x * blockDim.x + threadIdx.x; i < total;
         i += gridDim.x * blockDim.x) {
        if (i < W1P_DW) {
            int kb = i >> 9, rem = i & 511;
            int kg = rem >> 7, col_s = rem & 127;
            int col = (col_s - 8 * kg) & 127;
            unsigned d = 0;
#pragma unroll
            for (int j = 0; j < 8; ++j) {
                int k = kb * 32 + kg * 8 + j;
                unsigned q = 0;
                if (k < KIN) q = (unsigned)w1q[col * KIN + k] & 0xFu;
                d |= q << (4 * j);
            }
            w1p[i] = d;
        } else if (i < W1P_DW + W2C_ELEMS) {
            int t = i - W1P_DW;
            int kb = t >> 9, rem = t & 511;
            int col = rem >> 3, j = rem & 7;
            int k = kb * 8 + j;
            w2c[t] = __float2bfloat16((float)w2q[col * H1N + k] * s2[col]);
        } else {
            int t = i - W1P_DW - W2C_ELEMS;
            int r = t >> 6, c = t & 63;
            float v = 0.0f;
            if (r < OUTN) v = (float)w3q[r * H2N + c] * s3[r];
            w3d[t] = __float2bfloat16(v);
        }
    }
}

// ---------------- fused MLP ------------------------------------------------
// r14 structure (256 thr / 64-row tile / 2x2 wave decomposition / int4-B /
// counted vmcnt / 2 raw barriers / grid 2048), single change: 3-slot ring
// with WAITV(8) -> 3 windows (30KB/block) airborne instead of 2. LDS 30KB ->
// still 5 blocks/CU.
__global__ __launch_bounds__(256, 5) void mlp_kernel(
    const float* __restrict__ x,
    const unsigned* __restrict__ w1p,
    const bf16*  __restrict__ w2c,
    const bf16*  __restrict__ w3d,
    const float* __restrict__ s1,
    const float* __restrict__ b1,
    const float* __restrict__ b2,
    const float* __restrict__ b3,
    float* __restrict__ out)
{
    __shared__ __align__(16) char lds[30720];
    // A slots: s*8192, s=0..2 (64 rows x 128B, seg-swizzled)
    // B slots: 24576 + s*2048 (packed int4 window, 512 dwords [kg][col_s])
    // post-loop overlay: h1 [64][132] shorts at 0; h2 [64][68] at 16896.

    const int tid  = threadIdx.x;
    const int lane = tid & 63;
    const int wv   = tid >> 6;
    const int r16  = lane & 15;
    const int kg   = lane >> 4;     // 0..3
    const int kgo  = kg * 8;
    const int rg   = wv >> 1;       // row group (32 rows)
    const int cg   = wv & 1;        // col group (64 cols)

    const int i3 = lane >> 3;       // staging row-in-group 0..7
    const int i7 = lane & 7;        // staging 16B-slot 0..7
    const int sw = i7 ^ i3;         // swizzled global seg
    const int adj = (sw >= 4) ? 16 : 0;

    const long long rowBlk = (long long)blockIdx.x * 64;
    const float* gA0 = x + (rowBlk + wv * 16 + i3) * (long long)KIN + sw * 4;
    const float* gA1 = gA0 + 8LL * KIN;
    const unsigned* gBp = w1p + wv * 128 + lane;

    const int aoff = (rg * 32 + r16) * 128 + (((2 * kg) ^ (r16 & 7)) * 16);
    const int bcol = cg * 64 + r16 + 8 * kg;

    // stage window w into slot s (uniform 4 vmem ops per wave)
#define STAGE(W, S) do {                                                      \
        char* ad_ = lds + (S) * 8192 + wv * 2048;                             \
        char* bd_ = lds + 24576 + (S) * 2048 + wv * 512;                      \
        if ((W) < 24) {                                                       \
            gl2lds16(gA0 + (W) * 32, ad_);                                    \
            gl2lds16(gA1 + (W) * 32, ad_ + 1024);                             \
            gl2lds4(gBp + (W) * 512, bd_);                                    \
            gl2lds4(gBp + (W) * 512 + 64, bd_ + 256);                         \
        } else {            /* tail: A segs>=4 redirected in-row */           \
            gl2lds16(gA0 + 768 - adj, ad_);                                   \
            gl2lds16(gA1 + 768 - adj, ad_ + 1024);                            \
            gl2lds4(gBp + 24 * 512, bd_);                                     \
            gl2lds4(gBp + 24 * 512 + 64, bd_ + 256);                          \
        }                                                                     \
    } while (0)

    // prologue: windows 0,1,2 -> slots 0,1,2 (12 ops airborne)
    STAGE(0, 0);
    STAGE(1, 1);
    STAGE(2, 2);

    f32x4 acc1[2][4];
#pragma unroll
    for (int i = 0; i < 2; ++i)
#pragma unroll
        for (int j = 0; j < 4; ++j) acc1[i][j] = (f32x4){0.f, 0.f, 0.f, 0.f};

    int sc = 0;                     // consume slot
#pragma unroll 1
    for (int t = 0; t < 23; ++t) {
        WAITV(8);                 // window t landed; t+1,t+2 stay airborne
        BAR();                    // all waves' shares landed
        const char* sa = lds + sc * 8192;
        f32x4 q00 = *(const f32x4*)(sa + aoff);
        f32x4 q01 = *(const f32x4*)(sa + (aoff ^ 16));
        f32x4 q10 = *(const f32x4*)(sa + aoff + 2048);
        f32x4 q11 = *(const f32x4*)(sa + (aoff ^ 16) + 2048);
        const char* sb = lds + 24576 + sc * 2048 + kg * 512;
        unsigned bw4[4];
#pragma unroll
        for (int nj = 0; nj < 4; ++nj)
            bw4[nj] = *(const unsigned*)(sb + (((bcol + nj * 16) & 127) << 2));
        WAITL();                  // reads in registers
        BAR();                    // all waves done with slot sc
        if (t <= 21) STAGE(t + 3, sc);   // refill the just-freed slot
        s16x8 a0 = cvt8(q00, q01);
        s16x8 a1 = cvt8(q10, q11);
#pragma unroll
        for (int nj = 0; nj < 4; ++nj) {
            s16x8 bf = unpack8(bw4[nj]);
            acc1[0][nj] = __builtin_amdgcn_mfma_f32_16x16x32_bf16(a0, bf, acc1[0][nj], 0, 0, 0);
            acc1[1][nj] = __builtin_amdgcn_mfma_f32_16x16x32_bf16(a1, bf, acc1[1][nj], 0, 0, 0);
        }
        sc = (sc == 2) ? 0 : sc + 1;
    }
    {   // peeled t = 23 (window 23; outstanding 23,24 = 8 ops)
        WAITV(4);
        BAR();
        const char* sa = lds + sc * 8192;
        f32x4 q00 = *(const f32x4*)(sa + aoff);
        f32x4 q01 = *(const f32x4*)(sa + (aoff ^ 16));
        f32x4 q10 = *(const f32x4*)(sa + aoff + 2048);
        f32x4 q11 = *(const f32x4*)(sa + (aoff ^ 16) + 2048);
        const char* sb = lds + 24576 + sc * 2048 + kg * 512;
        unsigned bw4[4];
#pragma unroll
        for (int nj = 0; nj < 4; ++nj)
            bw4[nj] = *(const unsigned*)(sb + (((bcol + nj * 16) & 127) << 2));
        WAITL();
        BAR();
        s16x8 a0 = cvt8(q00, q01);
        s16x8 a1 = cvt8(q10, q11);
#pragma unroll
        for (int nj = 0; nj < 4; ++nj) {
            s16x8 bf = unpack8(bw4[nj]);
            acc1[0][nj] = __builtin_amdgcn_mfma_f32_16x16x32_bf16(a0, bf, acc1[0][nj], 0, 0, 0);
            acc1[1][nj] = __builtin_amdgcn_mfma_f32_16x16x32_bf16(a1, bf, acc1[1][nj], 0, 0, 0);
        }
        sc = (sc == 2) ? 0 : sc + 1;
    }
    {   // peeled t = 24 (window 24, k 768..799; packed weights zero k>=784)
        WAITV(0);
        BAR();
        const char* sa = lds + sc * 8192;
        f32x4 q00 = *(const f32x4*)(sa + aoff);
        f32x4 q01 = *(const f32x4*)(sa + (aoff ^ 16));
        f32x4 q10 = *(const f32x4*)(sa + aoff + 2048);
        f32x4 q11 = *(const f32x4*)(sa + (aoff ^ 16) + 2048);
        const char* sb = lds + 24576 + sc * 2048 + kg * 512;
        unsigned bw4[4];
#pragma unroll
        for (int nj = 0; nj < 4; ++nj)
            bw4[nj] = *(const unsigned*)(sb + (((bcol + nj * 16) & 127) << 2));
        WAITL();
        BAR();                    // ring fully dead -> arenas may overlay
        s16x8 a0 = cvt8(q00, q01);
        s16x8 a1 = cvt8(q10, q11);
#pragma unroll
        for (int nj = 0; nj < 4; ++nj) {
            s16x8 bf = unpack8(bw4[nj]);
            acc1[0][nj] = __builtin_amdgcn_mfma_f32_16x16x32_bf16(a0, bf, acc1[0][nj], 0, 0, 0);
            acc1[1][nj] = __builtin_amdgcn_mfma_f32_16x16x32_bf16(a1, bf, acc1[1][nj], 0, 0, 0);
        }
    }
#undef STAGE

    // ---- h1 (block-level [64][132] shorts at lds+0): scale+bias+relu -------
    short* h1s = (short*)lds;
#pragma unroll
    for (int nj = 0; nj < 4; ++nj) {
        const int col = cg * 64 + nj * 16 + r16;
        const float sc1 = s1[col];
        const float bb = b1[col];
#pragma unroll
        for (int mi = 0; mi < 2; ++mi)
#pragma unroll
            for (int r = 0; r < 4; ++r) {
                const int row = rg * 32 + mi * 16 + kg * 4 + r;
                h1s[row * 132 + col] = b2s(fmaxf(acc1[mi][nj][r] * sc1 + bb, 0.0f));
            }
    }
    __syncthreads();   // h1 rows cross wave boundaries

    // ---- layer 2: [16 x 128] @ [128 x 64] per wave (rows wv*16..) ----------
    f32x4 acc2[4];
#pragma unroll
    for (int j = 0; j < 4; ++j) acc2[j] = (f32x4){0.f, 0.f, 0.f, 0.f};

#pragma unroll
    for (int it = 0; it < 4; ++it) {
        const int kk = it * 32 + kgo;
        s16x8 a = *(const s16x8*)(h1s + (wv * 16 + r16) * 132 + kk);
        const bf16* bp2 = w2c + (size_t)(it * 4 + kg) * 512 + (size_t)r16 * 8;
#pragma unroll
        for (int nj = 0; nj < 4; ++nj) {
            s16x8 b = *(const s16x8*)(bp2 + nj * 128);
            acc2[nj] = __builtin_amdgcn_mfma_f32_16x16x32_bf16(a, b, acc2[nj], 0, 0, 0);
        }
    }

    // h2 at lds+16896: [64][68] shorts; wave writes/reads its own 16 rows
    short* h2s = (short*)(lds + 16896);
#pragma unroll
    for (int nj = 0; nj < 4; ++nj) {
        const int col = nj * 16 + r16;
        const float bb = b2[col];
#pragma unroll
        for (int r = 0; r < 4; ++r)
            h2s[(wv * 16 + kg * 4 + r) * 68 + col] = b2s(fmaxf(acc2[nj][r] + bb, 0.0f));
    }

    // ---- layer 3: [16 x 64] @ [64 x 16] (rows 10..15 of W3 zero) -----------
    f32x4 acc3 = (f32x4){0.f, 0.f, 0.f, 0.f};
#pragma unroll
    for (int it = 0; it < 2; ++it) {
        const int kk = it * 32 + kgo;
        s16x8 a = *(const s16x8*)(h2s + (wv * 16 + r16) * 68 + kk);
        s16x8 b = *(const s16x8*)(w3d + r16 * H2N + kk);
        acc3 = __builtin_amdgcn_mfma_f32_16x16x32_bf16(a, b, acc3, 0, 0, 0);
    }

    // out stage in wave's own (dead) h1 rows
    float* ob = (float*)(lds + (wv * 16) * 264);
    const float bb3 = (r16 < OUTN) ? b3[r16] : 0.0f;
#pragma unroll
    for (int r = 0; r < 4; ++r) {
        const int row = kg * 4 + r;
        if (r16 < OUTN) ob[row * OUTN + r16] = acc3[r] + bb3;
    }
    const long long obase = (rowBlk + wv * 16) * OUTN;
    for (int i = lane; i < 16 * OUTN; i += 64) out[obase + i] = ob[i];
}

extern "C" void kernel_launch(void* const* d_in, const int* in_sizes, int n_in,
                              void* d_out, int out_size, void* d_ws, size_t ws_size,
                              hipStream_t stream) {
    const float* x   = (const float*)d_in[0];
    const int*   w1q = (const int*)d_in[1];
    const float* s1  = (const float*)d_in[2];
    const float* b1  = (const float*)d_in[3];
    const int*   w2q = (const int*)d_in[4];
    const float* s2  = (const float*)d_in[5];
    const float* b2  = (const float*)d_in[6];
    const int*   w3q = (const int*)d_in[7];
    const float* s3  = (const float*)d_in[8];
    const float* b3  = (const float*)d_in[9];
    float* out = (float*)d_out;

    unsigned* w1p = (unsigned*)d_ws;           // 12800 dwords
    bf16* w2c = (bf16*)(w1p + W1P_DW);         // [16][64][8]
    bf16* w3d = w2c + W2C_ELEMS;               // [16][64]

    dequant_kernel<<<128, 256, 0, stream>>>(w1q, s1, w2q, s2, w3q, s3, w1p, w2c, w3d);
    mlp_kernel<<<NROWS / 64, 256, 0, stream>>>(x, w1p, w2c, w3d, s1, b1, b2, b3, out);
}